// Round 6
// baseline (186.094 us; speedup 1.0000x reference)
//
#include <hip/hip_runtime.h>
#include <hip/hip_bf16.h>

// Problem constants (AttentionConv2d): B=32, CIN=256, H=W=32 -> N=1024,
// DK=DV=128, HEADS=8 -> per-head d=16, OUT=256.
#define BATCH 32
#define CIN   256
#define NPOS  1024
#define DKC   128
#define DVC   128
#define HEADS 8
#define OUTC  256

typedef __bf16 bf16x8 __attribute__((ext_vector_type(8)));
typedef __bf16 bf16x4 __attribute__((ext_vector_type(4)));
typedef float  f32x4  __attribute__((ext_vector_type(4)));
typedef float  f32x16 __attribute__((ext_vector_type(16)));
typedef unsigned u32x4 __attribute__((ext_vector_type(4)));

// q pre-scale: dk^-0.5 * log2(e), so attention can use raw exp2.
#define QSCALE 0.3606737602f

__device__ inline bf16x8 load8(const __bf16* p) {
    return *reinterpret_cast<const bf16x8*>(p);
}
__device__ inline f32x4 fzero4() {
    f32x4 z;
#pragma unroll
    for (int i = 0; i < 4; ++i) z[i] = 0.0f;
    return z;
}
__device__ inline float fexp2(float x) {
#if __has_builtin(__builtin_amdgcn_exp2f)
    return __builtin_amdgcn_exp2f(x);
#else
    return exp2f(x);
#endif
}

// ---------------------------------------------------------------------------
// Kernel D: dtype detector (fp32-as-bf16 halfwords have huge exponents).
// ---------------------------------------------------------------------------
__global__ __launch_bounds__(256) void detect_dtype(const unsigned short* __restrict__ xraw,
                                                    int* __restrict__ flag) {
    __shared__ int s;
    if (threadIdx.x == 0) s = 0;
    __syncthreads();
    int cnt = 0;
#pragma unroll
    for (int j = 0; j < 64; ++j) {
        unsigned short u = xraw[threadIdx.x * 64 + j];
        unsigned int e = (u >> 7) & 0xFF;
        if (e >= 0x92) cnt++;
    }
    if (cnt) atomicAdd(&s, cnt);
    __syncthreads();
    if (threadIdx.x == 0) *flag = (s > 0) ? 1 : 0;
}

// ---------------------------------------------------------------------------
// Kernel C: convert all weight/bias tensors to canonical bf16 in one launch.
// Weights land in ONE contiguous wcat[512][256] (qkv rows 0..383, conv rows
// 384..511) and bcat[512] so the GEMM inner loop has no pointer selects.
// ---------------------------------------------------------------------------
#define CV_WQKV 98304                    // w_qkv 384*256 -> wcat[0..)
#define CV_WOUT (CV_WQKV + 32768)        // w_out 128*256 -> wcat[98304..)
#define CV_BQKV (CV_WOUT + 384)          // b_qkv -> bcat[0..384)
#define CV_BOUT (CV_BQKV + 128)          // b_out -> bcat[384..512)
#define CV_WATT (CV_BOUT + 16384)        // w_attn 128*128
#define CV_BATT (CV_WATT + 128)          // b_attn
__global__ __launch_bounds__(256) void convert_all(
    const void* __restrict__ w_qkv, const void* __restrict__ b_qkv,
    const void* __restrict__ w_attn, const void* __restrict__ b_attn,
    const void* __restrict__ w_out, const void* __restrict__ b_out,
    __bf16* __restrict__ wcat, __bf16* __restrict__ bcat,
    __bf16* __restrict__ w_attnc, __bf16* __restrict__ b_attnc,
    const int* __restrict__ flag) {
    int i = blockIdx.x * 256 + threadIdx.x;
    const void* src; __bf16* dst; int j;
    if      (i < CV_WQKV) { src = w_qkv;  j = i;           dst = wcat + i; }
    else if (i < CV_WOUT) { src = w_out;  j = i - CV_WQKV; dst = wcat + i; }
    else if (i < CV_BQKV) { src = b_qkv;  j = i - CV_WOUT; dst = bcat + j; }
    else if (i < CV_BOUT) { src = b_out;  j = i - CV_BQKV; dst = bcat + 384 + j; }
    else if (i < CV_WATT) { src = w_attn; j = i - CV_BOUT; dst = w_attnc + j; }
    else if (i < CV_BATT) { src = b_attn; j = i - CV_WATT; dst = b_attnc + j; }
    else return;
    if (*flag) *dst = (__bf16)((const float*)src)[j];
    else       *dst = ((const __bf16*)src)[j];
}

// ---------------------------------------------------------------------------
// Kernel 1 (v5): QKV+conv GEMM, fused x-transpose, OCCUPANCY-DESYNC version.
// Round-5 counters (MfmaUtil 6.8%, VALUBusy 7.4%, HBM 16%, occ 34%) showed
// pure un-hidden latency: 512 blocks = 2 barrier-lockstepped blocks/CU.
// Now rows split over blockIdx.z: grid (16 n, 32 b, 2 z) = 1024 blocks,
// each 512 thr / 8 waves x 32 rows (acc[2][4] = 32 AGPR).
// __launch_bounds__(512,6) -> 3 blocks/CU, 24 waves/CU, 3 independent
// barrier pipelines: staging of one block overlaps K-loops of the others.
// Rolling aA prefetch: reload aA[rt] for step k+1 right at its last use
// (zero extra registers). x staged twice (z=0,1) - L3-resident, cheap.
// ---------------------------------------------------------------------------
__global__ __launch_bounds__(512, 6) void qkv_conv_gemm4(
    const void* __restrict__ xv,      // [B][C][N] fp32 or bf16
    const __bf16* __restrict__ wcat,  // [512][256]
    const __bf16* __restrict__ bcat,  // [512]
    __bf16* __restrict__ q_ws,        // [B*H][N][16]
    __bf16* __restrict__ k_ws,        // [B*H][N][16]
    __bf16* __restrict__ v_ws,        // [B*H][16][N]
    void* __restrict__ out,           // [B][256][N], dtype per flag
    const int* __restrict__ flag)
{
    __shared__ __bf16 xs[64][264];    // 33792 B
    bool isf32 = (*flag != 0);
    int b   = blockIdx.y;
    int n0  = blockIdx.x * 64;
    int z   = blockIdx.z;
    int t   = threadIdx.x;
    int nl  = t & 63, cb = t >> 6;    // cb 0..7

#pragma unroll
    for (int cs = 0; cs < 32; ++cs) {
        int c = cs * 8 + cb;
        size_t gi = ((size_t)b * CIN + c) * NPOS + n0 + nl;
        float v = isf32 ? ((const float*)xv)[gi] : (float)((const __bf16*)xv)[gi];
        xs[nl][c] = (__bf16)v;
    }
    __syncthreads();

    int wave = t >> 6;
    int lane = t & 63;
    int quad = lane >> 4, colid = lane & 15;
    int row0 = z * 256 + wave * 32;

    const __bf16* wp = wcat + (size_t)(row0 + colid) * CIN + quad * 8;

    f32x4 acc[2][4];
#pragma unroll
    for (int rt = 0; rt < 2; ++rt)
#pragma unroll
        for (int st = 0; st < 4; ++st) acc[rt][st] = fzero4();

    // prologue: aA for k0 = 0
    bf16x8 aA[2];
#pragma unroll
    for (int rt = 0; rt < 2; ++rt)
        aA[rt] = load8(wp + (size_t)(rt * 16) * CIN);

#pragma unroll
    for (int k = 0; k < 8; ++k) {
        int k0 = k * 32;
        bf16x8 bB[4];
#pragma unroll
        for (int st = 0; st < 4; ++st)
            bB[st] = *reinterpret_cast<const bf16x8*>(&xs[st * 16 + colid][k0 + quad * 8]);
#pragma unroll
        for (int rt = 0; rt < 2; ++rt) {
            bf16x8 a = aA[rt];
            if (k < 7)  // rolling prefetch for step k+1 (issues before MFMAs)
                aA[rt] = load8(wp + (size_t)(rt * 16) * CIN + k0 + 32);
#pragma unroll
            for (int st = 0; st < 4; ++st)
                acc[rt][st] = __builtin_amdgcn_mfma_f32_16x16x32_bf16(a, bB[st], acc[rt][st], 0, 0, 0);
        }
    }

#pragma unroll
    for (int rt = 0; rt < 2; ++rt) {
        int obase = row0 + rt * 16;  // uniform per wave; 16 consecutive o
        float bias[4];
#pragma unroll
        for (int r = 0; r < 4; ++r) bias[r] = (float)bcat[obase + quad * 4 + r];

        if (obase < DKC) {                       // ---- q: [B*H][N][16]
            int h = obase >> 4;
            __bf16* qb = q_ws + (((size_t)b * HEADS + h) * NPOS + n0) * 16 + quad * 4;
#pragma unroll
            for (int st = 0; st < 4; ++st) {
                bf16x4 ov;
#pragma unroll
                for (int r = 0; r < 4; ++r)
                    ov[r] = (__bf16)((acc[rt][st][r] + bias[r]) * QSCALE);
                *reinterpret_cast<bf16x4*>(qb + (size_t)(st * 16 + colid) * 16) = ov;
            }
        } else if (obase < 2 * DKC) {            // ---- k: [B*H][N][16]
            int h = (obase - DKC) >> 4;
            __bf16* kb = k_ws + (((size_t)b * HEADS + h) * NPOS + n0) * 16 + quad * 4;
#pragma unroll
            for (int st = 0; st < 4; ++st) {
                bf16x4 ov;
#pragma unroll
                for (int r = 0; r < 4; ++r)
                    ov[r] = (__bf16)(acc[rt][st][r] + bias[r]);
                *reinterpret_cast<bf16x4*>(kb + (size_t)(st * 16 + colid) * 16) = ov;
            }
        } else if (obase < 384) {                // ---- v: [B*H][16][N]
            int h = (obase - 2 * DKC) >> 4;
            __bf16* vb = v_ws + (((size_t)b * HEADS + h) * 16 + quad * 4) * NPOS + n0 + colid;
#pragma unroll
            for (int r = 0; r < 4; ++r)
#pragma unroll
                for (int st = 0; st < 4; ++st)
                    vb[(size_t)r * NPOS + st * 16] = (__bf16)(acc[rt][st][r] + bias[r]);
        } else {                                  // ---- conv out: [B][0..128][N]
            int oc = obase - 384 + quad * 4;
#pragma unroll
            for (int r = 0; r < 4; ++r) {
                size_t ob = ((size_t)b * OUTC + oc + r) * NPOS + n0 + colid;
#pragma unroll
                for (int st = 0; st < 4; ++st) {
                    float v = acc[rt][st][r] + bias[r];
                    if (isf32) ((float*)out)[ob + st * 16] = v;
                    else       ((__bf16*)out)[ob + st * 16] = (__bf16)v;
                }
            }
        }
    }
}

// ---------------------------------------------------------------------------
// Kernel 2 (v7): fused attention + projection, 32-QUERY WAVES for occupancy.
// Round-4/5 analysis: VALUBusy ~50% = wall 2.2x VALU-issue; the limiter was
// grid=512 -> 2 blocks/CU. Now: wave owns 32 queries (single Q-frag, single
// acc), grid (b=32, N/32=32 tiles) = 1024 blocks, __launch_bounds__(512,6)
// -> 3 blocks/CU, 24 waves/CU -> VALU pipe approaches saturation.
//   XCD affinity: id = b + 32*tile -> id%8 = b%8; per-XCD K/V+q = 3 MB < L2.
//   One-window K/V register prefetch kept (T14), ~74 regs incl. acc, no spill.
//   QK^T: v_mfma_f32_32x32x16_bf16, C = hoisted zero16.
//   exp2 -> v_cvt_pk_bf16_f32 -> v_permlane32_swap_b32 -> PV B-frag (T12).
//   PV: A rows 0-15 = V[dv][key], rows 16-31 = 1.0 -> denominator free.
//   Epilogue: olds[32 q][128 ch] -> barrier -> 16 out-ch x 32 q per wave.
// ---------------------------------------------------------------------------
#define OSTR 136  // olds row stride in ch (272 B, 17x16B -> ~2-way reads)
__global__ __launch_bounds__(512, 6) void attention_kernel(
    const __bf16* __restrict__ q_ws,   // [B*H][N][16]
    const __bf16* __restrict__ k_ws,   // [B*H][N][16]
    const __bf16* __restrict__ v_ws,   // [B*H][16][N]
    const __bf16* __restrict__ w_attn, // [128][128]
    const __bf16* __restrict__ b_attn, // [128]
    void* __restrict__ out,            // [B][256][N], dtype per flag
    const int* __restrict__ flag)
{
    __shared__ __align__(16) __bf16 olds[32][OSTR];  // 8.7 KB
    int b    = blockIdx.x;
    int nq0  = blockIdx.y * 32;
    int wave = threadIdx.x >> 6;                 // = head h
    int lane = threadIdx.x & 63;
    int l5   = lane & 31, hi = lane >> 5;        // 32x32 frag coords
    int h    = wave;
    int bh   = b * HEADS + h;

    const __bf16* qp = q_ws + (size_t)bh * NPOS * 16;
    const __bf16* kp = k_ws + (size_t)bh * NPOS * 16;
    const __bf16* vp = v_ws + (size_t)bh * 16 * NPOS;

    // Q B-frag (32x32x16): lane holds Q[nq0+l5][hi*8 .. hi*8+7]
    bf16x8 qB = load8(qp + (size_t)(nq0 + l5) * 16 + hi * 8);

    // PV A-operand: rows 0-15 = V (dv = l5), rows 16-31 = 1.0 (denominator).
    bf16x8 vA0, vA1;
#pragma unroll
    for (int i = 0; i < 8; ++i) { vA0[i] = (__bf16)1.0f; vA1[i] = (__bf16)1.0f; }
    const __bf16* vrow = vp + (size_t)l5 * NPOS + hi * 8;  // valid when l5<16

    f32x16 zero16;
#pragma unroll
    for (int i = 0; i < 16; ++i) zero16[i] = 0.0f;
    f32x16 acc = zero16;

    // ---- window-0 operand loads (prologue of the prefetch pipeline)
    bf16x8 kA = load8(kp + (size_t)l5 * 16 + hi * 8);
    if (l5 < 16) {
        vA0 = load8(vrow);
        vA1 = load8(vrow + 16);
    }

#pragma unroll 2
    for (int nk0 = 0; nk0 < NPOS; nk0 += 32) {
        // ---- prefetch window n+1 (wraps to 0 on the last iteration)
        int nkn = (nk0 + 32) & (NPOS - 1);
        bf16x8 kA_n = load8(kp + (size_t)(nkn + l5) * 16 + hi * 8);
        bf16x8 vA0_n = vA0, vA1_n = vA1;   // lanes l5>=16 keep the 1.0 rows
        if (l5 < 16) {
            vA0_n = load8(vrow + nkn);
            vA1_n = load8(vrow + nkn + 16);
        }
        // ---- compute window n with the already-resident kA/vA0/vA1
        f32x16 st = __builtin_amdgcn_mfma_f32_32x32x16_bf16(kA, qB, zero16, 0, 0, 0);
        // st[reg]: key = nk0+(reg&3)+8*(reg>>2)+4*hi, query = nq0+l5
        unsigned w[8];
#pragma unroll
        for (int m = 0; m < 4; ++m) {
            float e0 = fexp2(st[4 * m + 0]);
            float e1 = fexp2(st[4 * m + 1]);
            float e2 = fexp2(st[4 * m + 2]);
            float e3 = fexp2(st[4 * m + 3]);
            unsigned lo, hw;
            asm("v_cvt_pk_bf16_f32 %0, %1, %2" : "=v"(lo) : "v"(e0), "v"(e1));
            asm("v_cvt_pk_bf16_f32 %0, %1, %2" : "=v"(hw) : "v"(e2), "v"(e3));
            w[2 * m]     = lo;
            w[2 * m + 1] = hw;
        }
        // Swap lane-halves: {w0..w3} = B-frag keys nk0+0..15,
        // {w4..w7} = keys nk0+16..31 (per-lane keys hi*8..hi*8+7).
        asm("v_permlane32_swap_b32 %0, %1" : "+v"(w[0]), "+v"(w[2]));
        asm("v_permlane32_swap_b32 %0, %1" : "+v"(w[1]), "+v"(w[3]));
        asm("v_permlane32_swap_b32 %0, %1" : "+v"(w[4]), "+v"(w[6]));
        asm("v_permlane32_swap_b32 %0, %1" : "+v"(w[5]), "+v"(w[7]));
        u32x4 t1 = {w[0], w[1], w[2], w[3]};
        u32x4 t2 = {w[4], w[5], w[6], w[7]};
        bf16x8 pB1 = __builtin_bit_cast(bf16x8, t1);
        bf16x8 pB2 = __builtin_bit_cast(bf16x8, t2);
        acc = __builtin_amdgcn_mfma_f32_32x32x16_bf16(vA0, pB1, acc, 0, 0, 0);
        acc = __builtin_amdgcn_mfma_f32_32x32x16_bf16(vA1, pB2, acc, 0, 0, 0);
        // ---- rotate
        kA = kA_n; vA0 = vA0_n; vA1 = vA1_n;
    }
    // acc rows: (reg&3)+8*(reg>>2)+4*hi, col = query = l5.
    // regs 0-7 -> rows 0-15 = O^T[dv][query]; regs 8-15 -> rows 16-31 = denom.
    float inv = 1.0f / acc[8];
    bf16x4 o0, o1;
#pragma unroll
    for (int r = 0; r < 4; ++r) {
        o0[r] = (__bf16)(acc[r] * inv);       // dv = r + 4*hi
        o1[r] = (__bf16)(acc[4 + r] * inv);   // dv = 8 + r + 4*hi
    }
    __bf16* ol = &olds[l5][h * 16 + 4 * hi];
    *reinterpret_cast<bf16x4*>(ol)     = o0;
    *reinterpret_cast<bf16x4*>(ol + 8) = o1;
    __syncthreads();

    // ---- projection: this wave computes out-channels [h*16, h*16+16) for
    // the block's 32 queries. A = w_attn rows (16B loads, L2-hot), B = olds.
    int quad = lane >> 4, colid = lane & 15;
    int row0 = h * 16;
    f32x4 pacc[2];
#pragma unroll
    for (int st = 0; st < 2; ++st) pacc[st] = fzero4();
#pragma unroll
    for (int k0 = 0; k0 < DVC; k0 += 32) {
        bf16x8 a = load8(w_attn + (size_t)(row0 + colid) * DVC + k0 + quad * 8);
#pragma unroll
        for (int st = 0; st < 2; ++st) {
            bf16x8 bb = *reinterpret_cast<const bf16x8*>(&olds[st * 16 + colid][k0 + quad * 8]);
            pacc[st] = __builtin_amdgcn_mfma_f32_16x16x32_bf16(a, bb, pacc[st], 0, 0, 0);
        }
    }
    bool isf32 = (*flag != 0);
#pragma unroll
    for (int r = 0; r < 4; ++r) {
        int o = row0 + quad * 4 + r;
        float bias = (float)b_attn[o];
#pragma unroll
        for (int st = 0; st < 2; ++st) {
            int n = nq0 + st * 16 + colid;
            float v = pacc[st][r] + bias;
            size_t oi = ((size_t)b * OUTC + DVC + o) * NPOS + n;
            if (isf32) ((float*)out)[oi] = v;
            else       ((__bf16*)out)[oi] = (__bf16)v;
        }
    }
}

// ---------------------------------------------------------------------------
// Workspace layout (bytes):
//   0       : flag (int)
//   1.00 MB : wcat [512][256] (256 KB)   1.50 MB : bcat [512]
//   1.75 MB : w_attnc (32 KB)            2.00 MB : b_attnc
//   28 MB   : q_ws (8 MB)   36 MB : k_ws (8 MB)   44 MB : v_ws (8 MB)
// ---------------------------------------------------------------------------
extern "C" void kernel_launch(void* const* d_in, const int* in_sizes, int n_in,
                              void* d_out, int out_size, void* d_ws, size_t ws_size,
                              hipStream_t stream) {
    const void* x      = d_in[0];
    const void* w_qkv  = d_in[1];
    const void* b_qkv  = d_in[2];
    const void* w_attn = d_in[3];
    const void* b_attn = d_in[4];
    const void* w_out  = d_in[5];
    const void* b_out  = d_in[6];

    char* ws = (char*)d_ws;
    int*    flag    = (int*)ws;
    __bf16* wcat    = (__bf16*)(ws + (1u << 20));
    __bf16* bcat    = (__bf16*)(ws + (3u << 19));
    __bf16* w_attnc = (__bf16*)(ws + (7u << 18));
    __bf16* b_attnc = (__bf16*)(ws + (1u << 21));
    __bf16* q_ws    = (__bf16*)(ws + (28u << 20));
    __bf16* k_ws    = (__bf16*)(ws + (36u << 20));
    __bf16* v_ws    = (__bf16*)(ws + (44u << 20));

    detect_dtype<<<1, 256, 0, stream>>>((const unsigned short*)x, flag);
    convert_all<<<(CV_BATT + 255) / 256, 256, 0, stream>>>(
        w_qkv, b_qkv, w_attn, b_attn, w_out, b_out,
        wcat, bcat, w_attnc, b_attnc, flag);

    qkv_conv_gemm4<<<dim3(NPOS / 64, BATCH, 2), 512, 0, stream>>>(
        x, wcat, bcat, q_ws, k_ws, v_ws, d_out, flag);
    attention_kernel<<<dim3(BATCH, NPOS / 32), 512, 0, stream>>>(
        q_ws, k_ws, v_ws, w_attnc, b_attnc, d_out, flag);
}

// Round 7
// 158.477 us; speedup vs baseline: 1.1743x; 1.1743x over previous
//
#include <hip/hip_runtime.h>
#include <hip/hip_bf16.h>

// Problem constants (AttentionConv2d): B=32, CIN=256, H=W=32 -> N=1024,
// DK=DV=128, HEADS=8 -> per-head d=16, OUT=256.
#define BATCH 32
#define CIN   256
#define NPOS  1024
#define DKC   128
#define DVC   128
#define HEADS 8
#define OUTC  256

typedef __bf16 bf16x8 __attribute__((ext_vector_type(8)));
typedef __bf16 bf16x4 __attribute__((ext_vector_type(4)));
typedef float  f32x4  __attribute__((ext_vector_type(4)));
typedef float  f32x16 __attribute__((ext_vector_type(16)));
typedef unsigned u32x4 __attribute__((ext_vector_type(4)));

// q pre-scale: dk^-0.5 * log2(e), so attention can use raw exp2.
#define QSCALE 0.3606737602f

__device__ inline bf16x8 load8(const __bf16* p) {
    return *reinterpret_cast<const bf16x8*>(p);
}
__device__ inline f32x4 fzero4() {
    f32x4 z;
#pragma unroll
    for (int i = 0; i < 4; ++i) z[i] = 0.0f;
    return z;
}
__device__ inline float fexp2(float x) {
#if __has_builtin(__builtin_amdgcn_exp2f)
    return __builtin_amdgcn_exp2f(x);
#else
    return exp2f(x);
#endif
}

// ---------------------------------------------------------------------------
// Kernel D: dtype detector (fp32-as-bf16 halfwords have huge exponents).
// ---------------------------------------------------------------------------
__global__ __launch_bounds__(256) void detect_dtype(const unsigned short* __restrict__ xraw,
                                                    int* __restrict__ flag) {
    __shared__ int s;
    if (threadIdx.x == 0) s = 0;
    __syncthreads();
    int cnt = 0;
#pragma unroll
    for (int j = 0; j < 64; ++j) {
        unsigned short u = xraw[threadIdx.x * 64 + j];
        unsigned int e = (u >> 7) & 0xFF;
        if (e >= 0x92) cnt++;
    }
    if (cnt) atomicAdd(&s, cnt);
    __syncthreads();
    if (threadIdx.x == 0) *flag = (s > 0) ? 1 : 0;
}

// ---------------------------------------------------------------------------
// Kernel C: convert all weight/bias tensors to canonical bf16 in one launch.
// Weights land in ONE contiguous wcat[512][256] (qkv rows 0..383, conv rows
// 384..511) and bcat[512] so the GEMM inner loop has no pointer selects.
// ---------------------------------------------------------------------------
#define CV_WQKV 98304                    // w_qkv 384*256 -> wcat[0..)
#define CV_WOUT (CV_WQKV + 32768)        // w_out 128*256 -> wcat[98304..)
#define CV_BQKV (CV_WOUT + 384)          // b_qkv -> bcat[0..384)
#define CV_BOUT (CV_BQKV + 128)          // b_out -> bcat[384..512)
#define CV_WATT (CV_BOUT + 16384)        // w_attn 128*128
#define CV_BATT (CV_WATT + 128)          // b_attn
__global__ __launch_bounds__(256) void convert_all(
    const void* __restrict__ w_qkv, const void* __restrict__ b_qkv,
    const void* __restrict__ w_attn, const void* __restrict__ b_attn,
    const void* __restrict__ w_out, const void* __restrict__ b_out,
    __bf16* __restrict__ wcat, __bf16* __restrict__ bcat,
    __bf16* __restrict__ w_attnc, __bf16* __restrict__ b_attnc,
    const int* __restrict__ flag) {
    int i = blockIdx.x * 256 + threadIdx.x;
    const void* src; __bf16* dst; int j;
    if      (i < CV_WQKV) { src = w_qkv;  j = i;           dst = wcat + i; }
    else if (i < CV_WOUT) { src = w_out;  j = i - CV_WQKV; dst = wcat + i; }
    else if (i < CV_BQKV) { src = b_qkv;  j = i - CV_WOUT; dst = bcat + j; }
    else if (i < CV_BOUT) { src = b_out;  j = i - CV_BQKV; dst = bcat + 384 + j; }
    else if (i < CV_WATT) { src = w_attn; j = i - CV_BOUT; dst = w_attnc + j; }
    else if (i < CV_BATT) { src = b_attn; j = i - CV_WATT; dst = b_attnc + j; }
    else return;
    if (*flag) *dst = (__bf16)((const float*)src)[j];
    else       *dst = ((const __bf16*)src)[j];
}

// ---------------------------------------------------------------------------
// Kernel 1 (v6): QKV+conv GEMM, fused x-transpose, FAT waves + operand
// PREFETCH. Round-6 taught: thin waves lose (qkv4 acc[2][4] ~47us); round-5
// qkv3 (fat acc[4][4], no prefetch) = 44us with every pipe idle (MfmaUtil
// 6.8, VALU 7.4, HBM 16%): each k-step serialized {issue 4 wcat + 4 LDS
// loads -> ~200-400cy wait -> 16 MFMA}. v6 = qkv3 + one-k-step register
// prefetch of BOTH operands (aA from wcat/L2, bB from LDS), issued before
// the MFMA burst, so the wait hides under 16 MFMAs x 16 waves/CU.
// grid (N/64=16, B=32) = 512 blocks, 512 thr / 8 waves x 64 rows,
// 2 blocks/CU. LDS xs[64][264] (33.8 KB), b128 reads conflict-free.
// ---------------------------------------------------------------------------
__global__ __launch_bounds__(512, 4) void qkv_conv_gemm5(
    const void* __restrict__ xv,      // [B][C][N] fp32 or bf16
    const __bf16* __restrict__ wcat,  // [512][256]
    const __bf16* __restrict__ bcat,  // [512]
    __bf16* __restrict__ q_ws,        // [B*H][N][16]
    __bf16* __restrict__ k_ws,        // [B*H][N][16]
    __bf16* __restrict__ v_ws,        // [B*H][16][N]
    void* __restrict__ out,           // [B][256][N], dtype per flag
    const int* __restrict__ flag)
{
    __shared__ __bf16 xs[64][264];    // 33792 B
    bool isf32 = (*flag != 0);
    int b   = blockIdx.y;
    int n0  = blockIdx.x * 64;
    int t   = threadIdx.x;
    int nl  = t & 63, cb = t >> 6;    // cb 0..7

#pragma unroll
    for (int cs = 0; cs < 32; ++cs) {
        int c = cs * 8 + cb;
        size_t gi = ((size_t)b * CIN + c) * NPOS + n0 + nl;
        float v = isf32 ? ((const float*)xv)[gi] : (float)((const __bf16*)xv)[gi];
        xs[nl][c] = (__bf16)v;
    }
    __syncthreads();

    int wave = t >> 6;
    int lane = t & 63;
    int quad = lane >> 4, colid = lane & 15;
    int row0 = (wave >> 2) * 256 + (wave & 3) * 64;

    const __bf16* wp = wcat + (size_t)(row0 + colid) * CIN + quad * 8;

    f32x4 acc[4][4];
#pragma unroll
    for (int rt = 0; rt < 4; ++rt)
#pragma unroll
        for (int st = 0; st < 4; ++st) acc[rt][st] = fzero4();

    // ---- prologue: operands for k-step 0
    bf16x8 aA[4], bB[4];
#pragma unroll
    for (int rt = 0; rt < 4; ++rt)
        aA[rt] = load8(wp + (size_t)(rt * 16) * CIN);
#pragma unroll
    for (int st = 0; st < 4; ++st)
        bB[st] = *reinterpret_cast<const bf16x8*>(&xs[st * 16 + colid][quad * 8]);

#pragma unroll
    for (int k = 0; k < 8; ++k) {
        int k0 = k * 32;
        // ---- prefetch operands for k-step k+1 BEFORE the MFMA burst
        bf16x8 aN[4], bN[4];
        if (k < 7) {
#pragma unroll
            for (int rt = 0; rt < 4; ++rt)
                aN[rt] = load8(wp + (size_t)(rt * 16) * CIN + k0 + 32);
#pragma unroll
            for (int st = 0; st < 4; ++st)
                bN[st] = *reinterpret_cast<const bf16x8*>(&xs[st * 16 + colid][k0 + 32 + quad * 8]);
        }
        // ---- compute k-step k with already-resident operands
#pragma unroll
        for (int rt = 0; rt < 4; ++rt)
#pragma unroll
            for (int st = 0; st < 4; ++st)
                acc[rt][st] = __builtin_amdgcn_mfma_f32_16x16x32_bf16(aA[rt], bB[st], acc[rt][st], 0, 0, 0);
        // ---- rotate
        if (k < 7) {
#pragma unroll
            for (int rt = 0; rt < 4; ++rt) aA[rt] = aN[rt];
#pragma unroll
            for (int st = 0; st < 4; ++st) bB[st] = bN[st];
        }
    }

#pragma unroll
    for (int rt = 0; rt < 4; ++rt) {
        int obase = row0 + rt * 16;  // uniform per wave; 16 consecutive o
        float bias[4];
#pragma unroll
        for (int r = 0; r < 4; ++r) bias[r] = (float)bcat[obase + quad * 4 + r];

        if (obase < DKC) {                       // ---- q: [B*H][N][16]
            int h = obase >> 4;
            __bf16* qb = q_ws + (((size_t)b * HEADS + h) * NPOS + n0) * 16 + quad * 4;
#pragma unroll
            for (int st = 0; st < 4; ++st) {
                bf16x4 ov;
#pragma unroll
                for (int r = 0; r < 4; ++r)
                    ov[r] = (__bf16)((acc[rt][st][r] + bias[r]) * QSCALE);
                *reinterpret_cast<bf16x4*>(qb + (size_t)(st * 16 + colid) * 16) = ov;
            }
        } else if (obase < 2 * DKC) {            // ---- k: [B*H][N][16]
            int h = (obase - DKC) >> 4;
            __bf16* kb = k_ws + (((size_t)b * HEADS + h) * NPOS + n0) * 16 + quad * 4;
#pragma unroll
            for (int st = 0; st < 4; ++st) {
                bf16x4 ov;
#pragma unroll
                for (int r = 0; r < 4; ++r)
                    ov[r] = (__bf16)(acc[rt][st][r] + bias[r]);
                *reinterpret_cast<bf16x4*>(kb + (size_t)(st * 16 + colid) * 16) = ov;
            }
        } else if (obase < 384) {                // ---- v: [B*H][16][N]
            int h = (obase - 2 * DKC) >> 4;
            __bf16* vb = v_ws + (((size_t)b * HEADS + h) * 16 + quad * 4) * NPOS + n0 + colid;
#pragma unroll
            for (int r = 0; r < 4; ++r)
#pragma unroll
                for (int st = 0; st < 4; ++st)
                    vb[(size_t)r * NPOS + st * 16] = (__bf16)(acc[rt][st][r] + bias[r]);
        } else {                                  // ---- conv out: [B][0..128][N]
            int oc = obase - 384 + quad * 4;
#pragma unroll
            for (int r = 0; r < 4; ++r) {
                size_t ob = ((size_t)b * OUTC + oc + r) * NPOS + n0 + colid;
#pragma unroll
                for (int st = 0; st < 4; ++st) {
                    float v = acc[rt][st][r] + bias[r];
                    if (isf32) ((float*)out)[ob + st * 16] = v;
                    else       ((__bf16*)out)[ob + st * 16] = (__bf16)v;
                }
            }
        }
    }
}

// ---------------------------------------------------------------------------
// Kernel 2 (v6 REVERT): fused attention + projection, 64-query waves,
// one-window K/V register prefetch. This exact config measured ~43-44 us
// (rounds 4/5); round-6's 32-query variant regressed to 61 us (per-window
// compute fell below prefetch latency). grid (b=32, N/64=16), block 512:
// wave = head, 64 queries per wave.
//   XCD affinity: id = b + 32*nc -> id%8 = b%8; per-XCD K/V = 2 MB < L2.
//   QK^T: v_mfma_f32_32x32x16_bf16, C = hoisted zero16.
//   exp2 -> v_cvt_pk_bf16_f32 -> v_permlane32_swap_b32 -> PV B-frag (T12).
//   PV: A rows 0-15 = V[dv][key], rows 16-31 = 1.0 -> denominator free.
//   Epilogue: olds[64 q][128 ch] -> barrier -> 16 out-ch x 64 q per wave.
// ---------------------------------------------------------------------------
#define OSTR 136  // olds row stride in ch (272 B, 17x16B -> conflict-free)
__global__ __launch_bounds__(512, 4) void attention_kernel(
    const __bf16* __restrict__ q_ws,   // [B*H][N][16]
    const __bf16* __restrict__ k_ws,   // [B*H][N][16]
    const __bf16* __restrict__ v_ws,   // [B*H][16][N]
    const __bf16* __restrict__ w_attn, // [128][128]
    const __bf16* __restrict__ b_attn, // [128]
    void* __restrict__ out,            // [B][256][N], dtype per flag
    const int* __restrict__ flag)
{
    __shared__ __align__(16) __bf16 olds[64][OSTR];  // 17.4 KB
    int b    = blockIdx.x;
    int nq0  = blockIdx.y * 64;
    int wave = threadIdx.x >> 6;                 // = head h
    int lane = threadIdx.x & 63;
    int l5   = lane & 31, hi = lane >> 5;        // 32x32 frag coords
    int h    = wave;
    int bh   = b * HEADS + h;

    const __bf16* qp = q_ws + (size_t)bh * NPOS * 16;
    const __bf16* kp = k_ws + (size_t)bh * NPOS * 16;
    const __bf16* vp = v_ws + (size_t)bh * 16 * NPOS;

    // Two Q B-frags (32x32x16): lane holds Q[nq][hi*8 .. hi*8+7]
    bf16x8 qB0 = load8(qp + (size_t)(nq0 + l5) * 16 + hi * 8);
    bf16x8 qB1 = load8(qp + (size_t)(nq0 + 32 + l5) * 16 + hi * 8);

    // PV A-operand: rows 0-15 = V (dv = l5), rows 16-31 = 1.0 (denominator).
    bf16x8 vA0, vA1;
#pragma unroll
    for (int i = 0; i < 8; ++i) { vA0[i] = (__bf16)1.0f; vA1[i] = (__bf16)1.0f; }
    const __bf16* vrow = vp + (size_t)l5 * NPOS + hi * 8;  // valid when l5<16

    f32x16 zero16;
#pragma unroll
    for (int i = 0; i < 16; ++i) zero16[i] = 0.0f;
    f32x16 acc0 = zero16, acc1 = zero16;

    // ---- window-0 operand loads (prologue of the prefetch pipeline)
    bf16x8 kA = load8(kp + (size_t)l5 * 16 + hi * 8);
    if (l5 < 16) {
        vA0 = load8(vrow);
        vA1 = load8(vrow + 16);
    }

#pragma unroll 2
    for (int nk0 = 0; nk0 < NPOS; nk0 += 32) {
        // ---- prefetch window n+1 (wraps to 0 on the last iteration)
        int nkn = (nk0 + 32) & (NPOS - 1);
        bf16x8 kA_n = load8(kp + (size_t)(nkn + l5) * 16 + hi * 8);
        bf16x8 vA0_n = vA0, vA1_n = vA1;   // lanes l5>=16 keep the 1.0 rows
        if (l5 < 16) {
            vA0_n = load8(vrow + nkn);
            vA1_n = load8(vrow + nkn + 16);
        }
        // ---- compute window n with the already-resident kA/vA0/vA1
#pragma unroll
        for (int half = 0; half < 2; ++half) {
            f32x16 st = __builtin_amdgcn_mfma_f32_32x32x16_bf16(
                kA, half ? qB1 : qB0, zero16, 0, 0, 0);
            // st[reg]: key = nk0+(reg&3)+8*(reg>>2)+4*hi, query = nq0+32*half+l5
            unsigned w[8];
#pragma unroll
            for (int m = 0; m < 4; ++m) {
                float e0 = fexp2(st[4 * m + 0]);
                float e1 = fexp2(st[4 * m + 1]);
                float e2 = fexp2(st[4 * m + 2]);
                float e3 = fexp2(st[4 * m + 3]);
                unsigned lo, hw;
                asm("v_cvt_pk_bf16_f32 %0, %1, %2" : "=v"(lo) : "v"(e0), "v"(e1));
                asm("v_cvt_pk_bf16_f32 %0, %1, %2" : "=v"(hw) : "v"(e2), "v"(e3));
                w[2 * m]     = lo;
                w[2 * m + 1] = hw;
            }
            // Swap lane-halves: {w0..w3} = B-frag keys nk0+0..15,
            // {w4..w7} = keys nk0+16..31 (per-lane keys hi*8..hi*8+7).
            asm("v_permlane32_swap_b32 %0, %1" : "+v"(w[0]), "+v"(w[2]));
            asm("v_permlane32_swap_b32 %0, %1" : "+v"(w[1]), "+v"(w[3]));
            asm("v_permlane32_swap_b32 %0, %1" : "+v"(w[4]), "+v"(w[6]));
            asm("v_permlane32_swap_b32 %0, %1" : "+v"(w[5]), "+v"(w[7]));
            u32x4 t1 = {w[0], w[1], w[2], w[3]};
            u32x4 t2 = {w[4], w[5], w[6], w[7]};
            bf16x8 pB1 = __builtin_bit_cast(bf16x8, t1);
            bf16x8 pB2 = __builtin_bit_cast(bf16x8, t2);
            if (half) {
                acc1 = __builtin_amdgcn_mfma_f32_32x32x16_bf16(vA0, pB1, acc1, 0, 0, 0);
                acc1 = __builtin_amdgcn_mfma_f32_32x32x16_bf16(vA1, pB2, acc1, 0, 0, 0);
            } else {
                acc0 = __builtin_amdgcn_mfma_f32_32x32x16_bf16(vA0, pB1, acc0, 0, 0, 0);
                acc0 = __builtin_amdgcn_mfma_f32_32x32x16_bf16(vA1, pB2, acc0, 0, 0, 0);
            }
        }
        // ---- rotate
        kA = kA_n; vA0 = vA0_n; vA1 = vA1_n;
    }
    // acc rows: (reg&3)+8*(reg>>2)+4*hi, col = query = l5.
    // regs 0-7 -> rows 0-15 = O^T[dv][query]; regs 8-15 -> rows 16-31 = denom.
    // Normalize and deposit this head's 16 dv channels into olds[q][h*16+dv].
#pragma unroll
    for (int half = 0; half < 2; ++half) {
        const f32x16& acc = half ? acc1 : acc0;
        float inv = 1.0f / acc[8];
        bf16x4 o0, o1;
#pragma unroll
        for (int r = 0; r < 4; ++r) {
            o0[r] = (__bf16)(acc[r] * inv);       // dv = r + 4*hi
            o1[r] = (__bf16)(acc[4 + r] * inv);   // dv = 8 + r + 4*hi
        }
        __bf16* ol = &olds[32 * half + l5][h * 16 + 4 * hi];
        *reinterpret_cast<bf16x4*>(ol)     = o0;
        *reinterpret_cast<bf16x4*>(ol + 8) = o1;
    }
    __syncthreads();

    // ---- projection: this wave computes out-channels [h*16, h*16+16) for
    // the block's 64 queries. A = w_attn rows (16B loads, L2-hot), B = olds.
    int quad = lane >> 4, colid = lane & 15;
    int row0 = h * 16;
    f32x4 pacc[4];
#pragma unroll
    for (int st = 0; st < 4; ++st) pacc[st] = fzero4();
#pragma unroll
    for (int k0 = 0; k0 < DVC; k0 += 32) {
        bf16x8 a = load8(w_attn + (size_t)(row0 + colid) * DVC + k0 + quad * 8);
#pragma unroll
        for (int st = 0; st < 4; ++st) {
            bf16x8 bb = *reinterpret_cast<const bf16x8*>(&olds[st * 16 + colid][k0 + quad * 8]);
            pacc[st] = __builtin_amdgcn_mfma_f32_16x16x32_bf16(a, bb, pacc[st], 0, 0, 0);
        }
    }
    bool isf32 = (*flag != 0);
#pragma unroll
    for (int r = 0; r < 4; ++r) {
        int o = row0 + quad * 4 + r;
        float bias = (float)b_attn[o];
#pragma unroll
        for (int st = 0; st < 4; ++st) {
            int n = nq0 + st * 16 + colid;
            float v = pacc[st][r] + bias;
            size_t oi = ((size_t)b * OUTC + DVC + o) * NPOS + n;
            if (isf32) ((float*)out)[oi] = v;
            else       ((__bf16*)out)[oi] = (__bf16)v;
        }
    }
}

// ---------------------------------------------------------------------------
// Workspace layout (bytes):
//   0       : flag (int)
//   1.00 MB : wcat [512][256] (256 KB)   1.50 MB : bcat [512]
//   1.75 MB : w_attnc (32 KB)            2.00 MB : b_attnc
//   28 MB   : q_ws (8 MB)   36 MB : k_ws (8 MB)   44 MB : v_ws (8 MB)
// ---------------------------------------------------------------------------
extern "C" void kernel_launch(void* const* d_in, const int* in_sizes, int n_in,
                              void* d_out, int out_size, void* d_ws, size_t ws_size,
                              hipStream_t stream) {
    const void* x      = d_in[0];
    const void* w_qkv  = d_in[1];
    const void* b_qkv  = d_in[2];
    const void* w_attn = d_in[3];
    const void* b_attn = d_in[4];
    const void* w_out  = d_in[5];
    const void* b_out  = d_in[6];

    char* ws = (char*)d_ws;
    int*    flag    = (int*)ws;
    __bf16* wcat    = (__bf16*)(ws + (1u << 20));
    __bf16* bcat    = (__bf16*)(ws + (3u << 19));
    __bf16* w_attnc = (__bf16*)(ws + (7u << 18));
    __bf16* b_attnc = (__bf16*)(ws + (1u << 21));
    __bf16* q_ws    = (__bf16*)(ws + (28u << 20));
    __bf16* k_ws    = (__bf16*)(ws + (36u << 20));
    __bf16* v_ws    = (__bf16*)(ws + (44u << 20));

    detect_dtype<<<1, 256, 0, stream>>>((const unsigned short*)x, flag);
    convert_all<<<(CV_BATT + 255) / 256, 256, 0, stream>>>(
        w_qkv, b_qkv, w_attn, b_attn, w_out, b_out,
        wcat, bcat, w_attnc, b_attnc, flag);

    qkv_conv_gemm5<<<dim3(NPOS / 64, BATCH), 512, 0, stream>>>(
        x, wcat, bcat, q_ws, k_ws, v_ws, d_out, flag);
    attention_kernel<<<dim3(BATCH, NPOS / 64), 512, 0, stream>>>(
        q_ws, k_ws, v_ws, w_attnc, b_attnc, d_out, flag);
}

// Round 8
// 158.154 us; speedup vs baseline: 1.1767x; 1.0020x over previous
//
#include <hip/hip_runtime.h>
#include <hip/hip_bf16.h>

// Problem constants (AttentionConv2d): B=32, CIN=256, H=W=32 -> N=1024,
// DK=DV=128, HEADS=8 -> per-head d=16, OUT=256.
#define BATCH 32
#define CIN   256
#define NPOS  1024
#define DKC   128
#define DVC   128
#define HEADS 8
#define OUTC  256

typedef __bf16 bf16x8 __attribute__((ext_vector_type(8)));
typedef __bf16 bf16x4 __attribute__((ext_vector_type(4)));
typedef float  f32x4  __attribute__((ext_vector_type(4)));
typedef float  f32x16 __attribute__((ext_vector_type(16)));
typedef unsigned u32x4 __attribute__((ext_vector_type(4)));
typedef unsigned short u16x8 __attribute__((ext_vector_type(8)));

// q pre-scale: dk^-0.5 * log2(e), so attention can use raw exp2.
#define QSCALE 0.3606737602f

__device__ inline bf16x8 load8(const __bf16* p) {
    return *reinterpret_cast<const bf16x8*>(p);
}
__device__ inline f32x4 fzero4() {
    f32x4 z;
#pragma unroll
    for (int i = 0; i < 4; ++i) z[i] = 0.0f;
    return z;
}
__device__ inline float fexp2(float x) {
#if __has_builtin(__builtin_amdgcn_exp2f)
    return __builtin_amdgcn_exp2f(x);
#else
    return exp2f(x);
#endif
}

// ---------------------------------------------------------------------------
// Kernel D (v2): dtype detector, COALESCED. Old version: 1 block x 256 thr,
// thread-stride-64 scalar reads -> every wave op hit 64 distinct cold
// cachelines from ONE CU = tens of us of serial latency (the hidden ~60us
// residual's prime suspect). Now: 1024 threads, short8 16B/lane coalesced,
// 64 KB scanned (32K halfwords; fp32 low-halfwords are random -> ~28% hit
// e>=0x92; bf16 N(0,1) data never does). ~3 us.
// ---------------------------------------------------------------------------
__global__ __launch_bounds__(1024) void detect_dtype(const unsigned short* __restrict__ xraw,
                                                     int* __restrict__ flag) {
    __shared__ int s;
    if (threadIdx.x == 0) s = 0;
    __syncthreads();
    int cnt = 0;
#pragma unroll
    for (int r = 0; r < 4; ++r) {
        u16x8 v = *reinterpret_cast<const u16x8*>(xraw + ((size_t)r * 1024 + threadIdx.x) * 8);
#pragma unroll
        for (int j = 0; j < 8; ++j) {
            unsigned int e = (v[j] >> 7) & 0xFF;
            if (e >= 0x92) cnt++;
        }
    }
    if (cnt) atomicAdd(&s, cnt);
    __syncthreads();
    if (threadIdx.x == 0) *flag = (s > 0) ? 1 : 0;
}

// ---------------------------------------------------------------------------
// Kernel C: convert all weight/bias tensors to canonical bf16 in one launch.
// Weights land in ONE contiguous wcat[512][256] (qkv rows 0..383, conv rows
// 384..511) and bcat[512] so the GEMM inner loop has no pointer selects.
// ---------------------------------------------------------------------------
#define CV_WQKV 98304                    // w_qkv 384*256 -> wcat[0..)
#define CV_WOUT (CV_WQKV + 32768)        // w_out 128*256 -> wcat[98304..)
#define CV_BQKV (CV_WOUT + 384)          // b_qkv -> bcat[0..384)
#define CV_BOUT (CV_BQKV + 128)          // b_out -> bcat[384..512)
#define CV_WATT (CV_BOUT + 16384)        // w_attn 128*128
#define CV_BATT (CV_WATT + 128)          // b_attn
__global__ __launch_bounds__(256) void convert_all(
    const void* __restrict__ w_qkv, const void* __restrict__ b_qkv,
    const void* __restrict__ w_attn, const void* __restrict__ b_attn,
    const void* __restrict__ w_out, const void* __restrict__ b_out,
    __bf16* __restrict__ wcat, __bf16* __restrict__ bcat,
    __bf16* __restrict__ w_attnc, __bf16* __restrict__ b_attnc,
    const int* __restrict__ flag) {
    int i = blockIdx.x * 256 + threadIdx.x;
    const void* src; __bf16* dst; int j;
    if      (i < CV_WQKV) { src = w_qkv;  j = i;           dst = wcat + i; }
    else if (i < CV_WOUT) { src = w_out;  j = i - CV_WQKV; dst = wcat + i; }
    else if (i < CV_BQKV) { src = b_qkv;  j = i - CV_WOUT; dst = bcat + j; }
    else if (i < CV_BOUT) { src = b_out;  j = i - CV_BQKV; dst = bcat + 384 + j; }
    else if (i < CV_WATT) { src = w_attn; j = i - CV_BOUT; dst = w_attnc + j; }
    else if (i < CV_BATT) { src = b_attn; j = i - CV_WATT; dst = b_attnc + j; }
    else return;
    if (*flag) *dst = (__bf16)((const float*)src)[j];
    else       *dst = ((const __bf16*)src)[j];
}

// ---------------------------------------------------------------------------
// Kernel 1 (v7 = measured-best v4/qkv3 REVERT + nt out-stores): QKV+conv
// GEMM with fused x-transpose. Round-7 proved the K-loop operand prefetch is
// a null (45.7 vs 44.0 without) -> reverted. Conv-out stores are
// NON-TEMPORAL: out is never re-read, so keep it out of L2 and let q/k/v
// stay resident for the attention kernel.
// grid (N/64=16, B=32) = 512 blocks, 512 thr / 8 waves x 64 rows,
// 2 blocks/CU. LDS xs[64][264] (33.8 KB), b128 reads conflict-free.
// ---------------------------------------------------------------------------
__global__ __launch_bounds__(512, 4) void qkv_conv_gemm3(
    const void* __restrict__ xv,      // [B][C][N] fp32 or bf16
    const __bf16* __restrict__ wcat,  // [512][256]
    const __bf16* __restrict__ bcat,  // [512]
    __bf16* __restrict__ q_ws,        // [B*H][N][16]
    __bf16* __restrict__ k_ws,        // [B*H][N][16]
    __bf16* __restrict__ v_ws,        // [B*H][16][N]
    void* __restrict__ out,           // [B][256][N], dtype per flag
    const int* __restrict__ flag)
{
    __shared__ __bf16 xs[64][264];    // 33792 B
    bool isf32 = (*flag != 0);
    int b   = blockIdx.y;
    int n0  = blockIdx.x * 64;
    int t   = threadIdx.x;
    int nl  = t & 63, cb = t >> 6;    // cb 0..7

#pragma unroll
    for (int cs = 0; cs < 32; ++cs) {
        int c = cs * 8 + cb;
        size_t gi = ((size_t)b * CIN + c) * NPOS + n0 + nl;
        float v = isf32 ? ((const float*)xv)[gi] : (float)((const __bf16*)xv)[gi];
        xs[nl][c] = (__bf16)v;
    }
    __syncthreads();

    int wave = t >> 6;
    int lane = t & 63;
    int quad = lane >> 4, colid = lane & 15;
    int row0 = (wave >> 2) * 256 + (wave & 3) * 64;

    const __bf16* wp = wcat + (size_t)(row0 + colid) * CIN + quad * 8;

    f32x4 acc[4][4];
#pragma unroll
    for (int rt = 0; rt < 4; ++rt)
#pragma unroll
        for (int st = 0; st < 4; ++st) acc[rt][st] = fzero4();

#pragma unroll
    for (int k0 = 0; k0 < CIN; k0 += 32) {
        bf16x8 aA[4], bB[4];
#pragma unroll
        for (int rt = 0; rt < 4; ++rt)
            aA[rt] = load8(wp + (size_t)(rt * 16) * CIN + k0);
#pragma unroll
        for (int st = 0; st < 4; ++st)
            bB[st] = *reinterpret_cast<const bf16x8*>(&xs[st * 16 + colid][k0 + quad * 8]);
#pragma unroll
        for (int rt = 0; rt < 4; ++rt)
#pragma unroll
            for (int st = 0; st < 4; ++st)
                acc[rt][st] = __builtin_amdgcn_mfma_f32_16x16x32_bf16(aA[rt], bB[st], acc[rt][st], 0, 0, 0);
    }

#pragma unroll
    for (int rt = 0; rt < 4; ++rt) {
        int obase = row0 + rt * 16;  // uniform per wave; 16 consecutive o
        float bias[4];
#pragma unroll
        for (int r = 0; r < 4; ++r) bias[r] = (float)bcat[obase + quad * 4 + r];

        if (obase < DKC) {                       // ---- q: [B*H][N][16]
            int h = obase >> 4;
            __bf16* qb = q_ws + (((size_t)b * HEADS + h) * NPOS + n0) * 16 + quad * 4;
#pragma unroll
            for (int st = 0; st < 4; ++st) {
                bf16x4 ov;
#pragma unroll
                for (int r = 0; r < 4; ++r)
                    ov[r] = (__bf16)((acc[rt][st][r] + bias[r]) * QSCALE);
                *reinterpret_cast<bf16x4*>(qb + (size_t)(st * 16 + colid) * 16) = ov;
            }
        } else if (obase < 2 * DKC) {            // ---- k: [B*H][N][16]
            int h = (obase - DKC) >> 4;
            __bf16* kb = k_ws + (((size_t)b * HEADS + h) * NPOS + n0) * 16 + quad * 4;
#pragma unroll
            for (int st = 0; st < 4; ++st) {
                bf16x4 ov;
#pragma unroll
                for (int r = 0; r < 4; ++r)
                    ov[r] = (__bf16)(acc[rt][st][r] + bias[r]);
                *reinterpret_cast<bf16x4*>(kb + (size_t)(st * 16 + colid) * 16) = ov;
            }
        } else if (obase < 384) {                // ---- v: [B*H][16][N]
            int h = (obase - 2 * DKC) >> 4;
            __bf16* vb = v_ws + (((size_t)b * HEADS + h) * 16 + quad * 4) * NPOS + n0 + colid;
#pragma unroll
            for (int r = 0; r < 4; ++r)
#pragma unroll
                for (int st = 0; st < 4; ++st)
                    vb[(size_t)r * NPOS + st * 16] = (__bf16)(acc[rt][st][r] + bias[r]);
        } else {                                  // ---- conv out: [B][0..128][N]
            int oc = obase - 384 + quad * 4;
#pragma unroll
            for (int r = 0; r < 4; ++r) {
                size_t ob = ((size_t)b * OUTC + oc + r) * NPOS + n0 + colid;
#pragma unroll
                for (int st = 0; st < 4; ++st) {
                    float v = acc[rt][st][r] + bias[r];
                    if (isf32) __builtin_nontemporal_store(v, (float*)out + ob + st * 16);
                    else       __builtin_nontemporal_store((__bf16)v, (__bf16*)out + ob + st * 16);
                }
            }
        }
    }
}

// ---------------------------------------------------------------------------
// Kernel 2 (v8 = measured-best structure + nt out-stores): fused attention +
// output projection, 64-query waves, one-window K/V register prefetch.
// grid (b=32, N/64=16), block 512: wave = head, 64 queries per wave.
//   XCD affinity: id = b + 32*nc -> id%8 = b%8; per-XCD K/V = 2 MB < L2.
//   QK^T: v_mfma_f32_32x32x16_bf16, C = hoisted zero16.
//   exp2 -> v_cvt_pk_bf16_f32 -> v_permlane32_swap_b32 -> PV B-frag (T12).
//   PV: A rows 0-15 = V[dv][key], rows 16-31 = 1.0 -> denominator free.
//   Epilogue: olds[64 q][128 ch] -> barrier -> 16 out-ch x 64 q per wave,
//   stored NON-TEMPORAL (out is never re-read).
// ---------------------------------------------------------------------------
#define OSTR 136  // olds row stride in ch (272 B, 17x16B -> conflict-free)
__global__ __launch_bounds__(512, 4) void attention_kernel(
    const __bf16* __restrict__ q_ws,   // [B*H][N][16]
    const __bf16* __restrict__ k_ws,   // [B*H][N][16]
    const __bf16* __restrict__ v_ws,   // [B*H][16][N]
    const __bf16* __restrict__ w_attn, // [128][128]
    const __bf16* __restrict__ b_attn, // [128]
    void* __restrict__ out,            // [B][256][N], dtype per flag
    const int* __restrict__ flag)
{
    __shared__ __align__(16) __bf16 olds[64][OSTR];  // 17.4 KB
    int b    = blockIdx.x;
    int nq0  = blockIdx.y * 64;
    int wave = threadIdx.x >> 6;                 // = head h
    int lane = threadIdx.x & 63;
    int l5   = lane & 31, hi = lane >> 5;        // 32x32 frag coords
    int h    = wave;
    int bh   = b * HEADS + h;

    const __bf16* qp = q_ws + (size_t)bh * NPOS * 16;
    const __bf16* kp = k_ws + (size_t)bh * NPOS * 16;
    const __bf16* vp = v_ws + (size_t)bh * 16 * NPOS;

    // Two Q B-frags (32x32x16): lane holds Q[nq][hi*8 .. hi*8+7]
    bf16x8 qB0 = load8(qp + (size_t)(nq0 + l5) * 16 + hi * 8);
    bf16x8 qB1 = load8(qp + (size_t)(nq0 + 32 + l5) * 16 + hi * 8);

    // PV A-operand: rows 0-15 = V (dv = l5), rows 16-31 = 1.0 (denominator).
    bf16x8 vA0, vA1;
#pragma unroll
    for (int i = 0; i < 8; ++i) { vA0[i] = (__bf16)1.0f; vA1[i] = (__bf16)1.0f; }
    const __bf16* vrow = vp + (size_t)l5 * NPOS + hi * 8;  // valid when l5<16

    f32x16 zero16;
#pragma unroll
    for (int i = 0; i < 16; ++i) zero16[i] = 0.0f;
    f32x16 acc0 = zero16, acc1 = zero16;

    // ---- window-0 operand loads (prologue of the prefetch pipeline)
    bf16x8 kA = load8(kp + (size_t)l5 * 16 + hi * 8);
    if (l5 < 16) {
        vA0 = load8(vrow);
        vA1 = load8(vrow + 16);
    }

#pragma unroll 2
    for (int nk0 = 0; nk0 < NPOS; nk0 += 32) {
        // ---- prefetch window n+1 (wraps to 0 on the last iteration)
        int nkn = (nk0 + 32) & (NPOS - 1);
        bf16x8 kA_n = load8(kp + (size_t)(nkn + l5) * 16 + hi * 8);
        bf16x8 vA0_n = vA0, vA1_n = vA1;   // lanes l5>=16 keep the 1.0 rows
        if (l5 < 16) {
            vA0_n = load8(vrow + nkn);
            vA1_n = load8(vrow + nkn + 16);
        }
        // ---- compute window n with the already-resident kA/vA0/vA1
#pragma unroll
        for (int half = 0; half < 2; ++half) {
            f32x16 st = __builtin_amdgcn_mfma_f32_32x32x16_bf16(
                kA, half ? qB1 : qB0, zero16, 0, 0, 0);
            // st[reg]: key = nk0+(reg&3)+8*(reg>>2)+4*hi, query = nq0+32*half+l5
            unsigned w[8];
#pragma unroll
            for (int m = 0; m < 4; ++m) {
                float e0 = fexp2(st[4 * m + 0]);
                float e1 = fexp2(st[4 * m + 1]);
                float e2 = fexp2(st[4 * m + 2]);
                float e3 = fexp2(st[4 * m + 3]);
                unsigned lo, hw;
                asm("v_cvt_pk_bf16_f32 %0, %1, %2" : "=v"(lo) : "v"(e0), "v"(e1));
                asm("v_cvt_pk_bf16_f32 %0, %1, %2" : "=v"(hw) : "v"(e2), "v"(e3));
                w[2 * m]     = lo;
                w[2 * m + 1] = hw;
            }
            // Swap lane-halves: {w0..w3} = B-frag keys nk0+0..15,
            // {w4..w7} = keys nk0+16..31 (per-lane keys hi*8..hi*8+7).
            asm("v_permlane32_swap_b32 %0, %1" : "+v"(w[0]), "+v"(w[2]));
            asm("v_permlane32_swap_b32 %0, %1" : "+v"(w[1]), "+v"(w[3]));
            asm("v_permlane32_swap_b32 %0, %1" : "+v"(w[4]), "+v"(w[6]));
            asm("v_permlane32_swap_b32 %0, %1" : "+v"(w[5]), "+v"(w[7]));
            u32x4 t1 = {w[0], w[1], w[2], w[3]};
            u32x4 t2 = {w[4], w[5], w[6], w[7]};
            bf16x8 pB1 = __builtin_bit_cast(bf16x8, t1);
            bf16x8 pB2 = __builtin_bit_cast(bf16x8, t2);
            if (half) {
                acc1 = __builtin_amdgcn_mfma_f32_32x32x16_bf16(vA0, pB1, acc1, 0, 0, 0);
                acc1 = __builtin_amdgcn_mfma_f32_32x32x16_bf16(vA1, pB2, acc1, 0, 0, 0);
            } else {
                acc0 = __builtin_amdgcn_mfma_f32_32x32x16_bf16(vA0, pB1, acc0, 0, 0, 0);
                acc0 = __builtin_amdgcn_mfma_f32_32x32x16_bf16(vA1, pB2, acc0, 0, 0, 0);
            }
        }
        // ---- rotate
        kA = kA_n; vA0 = vA0_n; vA1 = vA1_n;
    }
    // acc rows: (reg&3)+8*(reg>>2)+4*hi, col = query = l5.
    // regs 0-7 -> rows 0-15 = O^T[dv][query]; regs 8-15 -> rows 16-31 = denom.
    // Normalize and deposit this head's 16 dv channels into olds[q][h*16+dv].
#pragma unroll
    for (int half = 0; half < 2; ++half) {
        const f32x16& acc = half ? acc1 : acc0;
        float inv = 1.0f / acc[8];
        bf16x4 o0, o1;
#pragma unroll
        for (int r = 0; r < 4; ++r) {
            o0[r] = (__bf16)(acc[r] * inv);       // dv = r + 4*hi
            o1[r] = (__bf16)(acc[4 + r] * inv);   // dv = 8 + r + 4*hi
        }
        __bf16* ol = &olds[32 * half + l5][h * 16 + 4 * hi];
        *reinterpret_cast<bf16x4*>(ol)     = o0;
        *reinterpret_cast<bf16x4*>(ol + 8) = o1;
    }
    __syncthreads();

    // ---- projection: this wave computes out-channels [h*16, h*16+16) for
    // the block's 64 queries. A = w_attn rows (16B loads, L2-hot), B = olds.
    int quad = lane >> 4, colid = lane & 15;
    int row0 = h * 16;
    f32x4 pacc[4];
#pragma unroll
    for (int st = 0; st < 4; ++st) pacc[st] = fzero4();
#pragma unroll
    for (int k0 = 0; k0 < DVC; k0 += 32) {
        bf16x8 a = load8(w_attn + (size_t)(row0 + colid) * DVC + k0 + quad * 8);
#pragma unroll
        for (int st = 0; st < 4; ++st) {
            bf16x8 bb = *reinterpret_cast<const bf16x8*>(&olds[st * 16 + colid][k0 + quad * 8]);
            pacc[st] = __builtin_amdgcn_mfma_f32_16x16x32_bf16(a, bb, pacc[st], 0, 0, 0);
        }
    }
    bool isf32 = (*flag != 0);
#pragma unroll
    for (int r = 0; r < 4; ++r) {
        int o = row0 + quad * 4 + r;
        float bias = (float)b_attn[o];
#pragma unroll
        for (int st = 0; st < 4; ++st) {
            int n = nq0 + st * 16 + colid;
            float v = pacc[st][r] + bias;
            size_t oi = ((size_t)b * OUTC + DVC + o) * NPOS + n;
            if (isf32) __builtin_nontemporal_store(v, (float*)out + oi);
            else       __builtin_nontemporal_store((__bf16)v, (__bf16*)out + oi);
        }
    }
}

// ---------------------------------------------------------------------------
// Workspace layout (bytes):
//   0       : flag (int)
//   1.00 MB : wcat [512][256] (256 KB)   1.50 MB : bcat [512]
//   1.75 MB : w_attnc (32 KB)            2.00 MB : b_attnc
//   28 MB   : q_ws (8 MB)   36 MB : k_ws (8 MB)   44 MB : v_ws (8 MB)
// ---------------------------------------------------------------------------
extern "C" void kernel_launch(void* const* d_in, const int* in_sizes, int n_in,
                              void* d_out, int out_size, void* d_ws, size_t ws_size,
                              hipStream_t stream) {
    const void* x      = d_in[0];
    const void* w_qkv  = d_in[1];
    const void* b_qkv  = d_in[2];
    const void* w_attn = d_in[3];
    const void* b_attn = d_in[4];
    const void* w_out  = d_in[5];
    const void* b_out  = d_in[6];

    char* ws = (char*)d_ws;
    int*    flag    = (int*)ws;
    __bf16* wcat    = (__bf16*)(ws + (1u << 20));
    __bf16* bcat    = (__bf16*)(ws + (3u << 19));
    __bf16* w_attnc = (__bf16*)(ws + (7u << 18));
    __bf16* b_attnc = (__bf16*)(ws + (1u << 21));
    __bf16* q_ws    = (__bf16*)(ws + (28u << 20));
    __bf16* k_ws    = (__bf16*)(ws + (36u << 20));
    __bf16* v_ws    = (__bf16*)(ws + (44u << 20));

    detect_dtype<<<1, 1024, 0, stream>>>((const unsigned short*)x, flag);
    convert_all<<<(CV_BATT + 255) / 256, 256, 0, stream>>>(
        w_qkv, b_qkv, w_attn, b_attn, w_out, b_out,
        wcat, bcat, w_attnc, b_attnc, flag);

    qkv_conv_gemm3<<<dim3(NPOS / 64, BATCH), 512, 0, stream>>>(
        x, wcat, bcat, q_ws, k_ws, v_ws, d_out, flag);
    attention_kernel<<<dim3(BATCH, NPOS / 64), 512, 0, stream>>>(
        q_ws, k_ws, v_ws, w_attnc, b_attnc, d_out, flag);
}